// Round 1
// baseline (257.412 us; speedup 1.0000x reference)
//
#include <hip/hip_runtime.h>
#include <hip/hip_bf16.h>

// RBF kernel: out[bn][m] = exp(-||z[m]-mu[bn]||^2 / (2*clip(sigma)^2))
// P = 2 (hardcoded). Store-BW bound: 256 MB fp32 output.
//
// Strategy: one block per (b,n) row. mu/sigma loaded once (uniform per block),
// exponent scale precomputed as c = log2(e)/(2 sig^2) so the inner loop is
// sub/sub/mul/fma/mul + v_exp_f32 per element, float4 stores.

#define MIN_SIGMA 0.1f
#define MAX_SIGMA 10.0f
#define LOG2E 1.44269504088896340736f

__global__ __launch_bounds__(256) void rbf_rows(
    const float* __restrict__ z,      // [M, 2]
    const float* __restrict__ mu,     // [BN, 2]
    const float* __restrict__ sigma,  // [BN]
    float* __restrict__ out,          // [BN, M]
    int M) {
  const int bn = blockIdx.x;

  // Wave-uniform loads (same address across block -> broadcast)
  const float mu0 = mu[2 * bn];
  const float mu1 = mu[2 * bn + 1];
  float sig = sigma[bn];
  sig = fminf(fmaxf(sig, MIN_SIGMA), MAX_SIGMA);
  const float c = LOG2E / (2.0f * sig * sig);  // exp(-d2/(2s^2)) = 2^(-d2*c)

  const float4* __restrict__ z4 = reinterpret_cast<const float4*>(z);
  float4* __restrict__ out4 =
      reinterpret_cast<float4*>(out + (size_t)bn * (size_t)M);
  const int nf4 = M >> 2;  // float4s per row (1024 for M=4096)

  for (int i = threadIdx.x; i < nf4; i += 256) {
    // z4[2i]   = (z[4i].x,  z[4i].y,  z[4i+1].x, z[4i+1].y)
    // z4[2i+1] = (z[4i+2].x,z[4i+2].y,z[4i+3].x, z[4i+3].y)
    const float4 za = z4[2 * i];
    const float4 zb = z4[2 * i + 1];
    float4 r;
    {
      const float dx = za.x - mu0, dy = za.y - mu1;
      r.x = __builtin_amdgcn_exp2f(-(dx * dx + dy * dy) * c);
    }
    {
      const float dx = za.z - mu0, dy = za.w - mu1;
      r.y = __builtin_amdgcn_exp2f(-(dx * dx + dy * dy) * c);
    }
    {
      const float dx = zb.x - mu0, dy = zb.y - mu1;
      r.z = __builtin_amdgcn_exp2f(-(dx * dx + dy * dy) * c);
    }
    {
      const float dx = zb.z - mu0, dy = zb.w - mu1;
      r.w = __builtin_amdgcn_exp2f(-(dx * dx + dy * dy) * c);
    }
    out4[i] = r;
  }
}

extern "C" void kernel_launch(void* const* d_in, const int* in_sizes, int n_in,
                              void* d_out, int out_size, void* d_ws,
                              size_t ws_size, hipStream_t stream) {
  const float* z = (const float*)d_in[0];      // [M, 2]
  const float* mu = (const float*)d_in[1];     // [B, N, 2] -> [BN, 2]
  const float* sigma = (const float*)d_in[2];  // [B, N, 1] -> [BN]
  float* out = (float*)d_out;                  // [BN, M]

  const int M = in_sizes[0] / 2;   // 4096
  const int BN = in_sizes[1] / 2;  // 16384

  rbf_rows<<<dim3(BN), dim3(256), 0, stream>>>(z, mu, sigma, out, M);
}